// Round 1
// baseline (1059.782 us; speedup 1.0000x reference)
//
#include <hip/hip_runtime.h>
#include <cstddef>

// RecurrentFRAdamaxAttention fused kernel.
// Shapes: N=1024, H=8, D=64, M=64. All fp32.
// One workgroup per (n,h): elementwise state update + two Frobenius-norm
// reductions + Q.Zi_new dot + V = Z * (Q^T Si) reduction, all fused so the
// five big (D,M) inputs are read exactly once and five outputs written once.
// HBM traffic ~1.36 GB -> memory-bound, roofline ~215 us @ 6.3 TB/s.

namespace {

constexpr float EPS      = 1e-6f;
constexpr float STEPSIZE = 0.5f;
constexpr float BETA     = 0.9f;
constexpr float DELTA    = 0.001f;

constexpr size_t NHD  = 1024ull * 8 * 64;        // 524288
constexpr size_t NHDM = 1024ull * 8 * 64 * 64;   // 33554432

// Output layout (concatenated flat, reference return order):
// (V, Si, Zi_new, Pi_new, Mi_new, Ui, Siprev)
constexpr size_t OFF_V  = 0;
constexpr size_t OFF_SI = OFF_V  + NHD;    // 524288
constexpr size_t OFF_ZN = OFF_SI + NHDM;   // 34078720
constexpr size_t OFF_PN = OFF_ZN + NHD;    // 34603008
constexpr size_t OFF_MN = OFF_PN + NHDM;   // 68157440
constexpr size_t OFF_UI = OFF_MN + NHDM;   // 101711872
constexpr size_t OFF_SP = OFF_UI + NHDM;   // 135266304

__device__ __forceinline__ float featmap(float x) {
    // elu(x) + 1 == (x > 0 ? x + 1 : exp(x))
    return x > 0.0f ? x + 1.0f : __expf(x);
}

} // namespace

__global__ __launch_bounds__(256)
void fra_adamax_fused(const float* __restrict__ query,
                      const float* __restrict__ key,
                      const float* __restrict__ value,
                      const float* __restrict__ Siprev,
                      const float* __restrict__ Zi,
                      const float* __restrict__ Pi,
                      const float* __restrict__ Mi,
                      const float* __restrict__ Uiprev,
                      const float* __restrict__ Siprev2,
                      float* __restrict__ out)
{
    __shared__ float  Qf[64];
    __shared__ float  Kf[64];
    __shared__ float4 Vl4[16];      // value row (64 floats)
    __shared__ float4 Sl[1024];     // Q[d] * Si staging (16 KiB)
    __shared__ float  red[12];      // 4 wave partials x {du, ds, qz}
    __shared__ float  bro[2];       // {mu, Z}
    __shared__ float  vred[256];    // V partial sums

    const int    t   = threadIdx.x;
    const int    nh  = blockIdx.x;
    const size_t vb  = (size_t)nh * 64;     // base into (N,H,D)-shaped arrays
    const size_t mb4 = (size_t)nh * 1024;   // base into (N,H,D,M), float4 units

    // ---- Phase A: feature maps + Zi_new + value row into LDS --------------
    float qz = 0.0f;
    if (t < 64) {
        float q  = featmap(query[vb + t]);
        float k  = featmap(key[vb + t]);
        float zn = Zi[vb + t] + k;
        Qf[t] = q;
        Kf[t] = k;
        out[OFF_ZN + vb + t] = zn;
        qz = q * zn;                        // partial of dot(Q, Zi_new)
    } else if (t < 128) {
        ((float*)Vl4)[t - 64] = value[vb + (t - 64)];
    }
    __syncthreads();

    const float4* Sp4  = (const float4*)Siprev  + mb4;
    const float4* Up4  = (const float4*)Uiprev  + mb4;
    const float4* Sp24 = (const float4*)Siprev2 + mb4;
    float4* oUi = (float4*)(out + OFF_UI) + mb4;
    float4* oSp = (float4*)(out + OFF_SP) + mb4;

    // ---- Phase B: Ui = K (x) value; norm partials; stream Ui & Siprev ------
    float4 ui[4], sp[4];
    float du = 0.0f, ds = 0.0f;
    #pragma unroll
    for (int j = 0; j < 4; ++j) {
        const int f4 = j * 256 + t;         // float4 index in [0,1024)
        const int d  = f4 >> 4;             // row (16 float4 per row of 64)
        const int mq = f4 & 15;             // float4 column
        const float  kd = Kf[d];
        const float4 v  = Vl4[mq];

        float4 u;
        u.x = kd * v.x; u.y = kd * v.y; u.z = kd * v.z; u.w = kd * v.w;

        const float4 up = Up4[f4];
        const float4 s  = Sp4[f4];
        const float4 s2 = Sp24[f4];

        float ex = u.x - up.x, ey = u.y - up.y, ez = u.z - up.z, ew = u.w - up.w;
        du += ex * ex + ey * ey + ez * ez + ew * ew;
        float fx = s.x - s2.x, fy = s.y - s2.y, fz = s.z - s2.z, fw = s.w - s2.w;
        ds += fx * fx + fy * fy + fz * fz + fw * fw;

        ui[j] = u;
        sp[j] = s;
        oUi[f4] = u;    // output: Ui
        oSp[f4] = s;    // output: Siprev (pass-through copy)
    }

    // ---- Phase C: block reduction -> mu, Z --------------------------------
    #pragma unroll
    for (int off = 32; off > 0; off >>= 1) {
        du += __shfl_down(du, off);
        ds += __shfl_down(ds, off);
        qz += __shfl_down(qz, off);
    }
    const int wave = t >> 6;
    if ((t & 63) == 0) {
        red[wave]     = du;
        red[4 + wave] = ds;
        red[8 + wave] = qz;
    }
    __syncthreads();
    if (t == 0) {
        const float DU = red[0] + red[1] + red[2]  + red[3];
        const float DS = red[4] + red[5] + red[6]  + red[7];
        const float QZ = red[8] + red[9] + red[10] + red[11];
        const float n1 = sqrtf(DU);
        const float n2 = sqrtf(DS);
        const float r  = sqrtf(STEPSIZE * n1 / n2);
        const float om = 1.0f - r;
        float mu = om * om;
        mu = fminf(mu, 1.0f - DELTA);
        mu = fmaxf(mu, 0.0f);
        bro[0] = mu;
        bro[1] = 1.0f / (QZ + EPS);
    }
    __syncthreads();
    const float mu = bro[0];
    const float Z  = bro[1];

    const float4* Pi4 = (const float4*)Pi + mb4;
    const float4* Mi4 = (const float4*)Mi + mb4;
    float4* oSi = (float4*)(out + OFF_SI) + mb4;
    float4* oPn = (float4*)(out + OFF_PN) + mb4;
    float4* oMn = (float4*)(out + OFF_MN) + mb4;

    // ---- Phase D: Pi_new / Mi_new / Si; stage Q[d]*Si in LDS --------------
    #pragma unroll
    for (int j = 0; j < 4; ++j) {
        const int f4 = j * 256 + t;
        const int d  = f4 >> 4;
        const float qd = Qf[d];
        const float4 p = Pi4[f4];
        const float4 m = Mi4[f4];
        const float4 u = ui[j];
        const float4 s = sp[j];

        float4 pn;
        pn.x = mu * p.x - STEPSIZE * u.x;
        pn.y = mu * p.y - STEPSIZE * u.y;
        pn.z = mu * p.z - STEPSIZE * u.z;
        pn.w = mu * p.w - STEPSIZE * u.w;

        float4 mn;
        mn.x = fmaxf(BETA * m.x, fabsf(u.x));
        mn.y = fmaxf(BETA * m.y, fabsf(u.y));
        mn.z = fmaxf(BETA * m.z, fabsf(u.z));
        mn.w = fmaxf(BETA * m.w, fabsf(u.w));

        float4 si;
        si.x = s.x - pn.x * rsqrtf(mn.x + 1e-16f);
        si.y = s.y - pn.y * rsqrtf(mn.y + 1e-16f);
        si.z = s.z - pn.z * rsqrtf(mn.z + 1e-16f);
        si.w = s.w - pn.w * rsqrtf(mn.w + 1e-16f);

        float4 qs;
        qs.x = qd * si.x; qs.y = qd * si.y; qs.z = qd * si.z; qs.w = qd * si.w;

        oPn[f4] = pn;
        oMn[f4] = mn;
        oSi[f4] = si;
        Sl[f4]  = qs;
    }
    __syncthreads();

    // ---- Phase E: V[m] = Z * sum_d Q[d]*Si[d][m] --------------------------
    {
        const int m  = t & 63;
        const int d0 = (t >> 6) * 16;
        const float* S = (const float*)Sl;
        float acc = 0.0f;
        #pragma unroll
        for (int d = 0; d < 16; ++d)
            acc += S[(d0 + d) * 64 + m];
        vred[t] = acc;
    }
    __syncthreads();
    if (t < 64) {
        const float v = vred[t] + vred[t + 64] + vred[t + 128] + vred[t + 192];
        out[OFF_V + vb + t] = Z * v;
    }
}

extern "C" void kernel_launch(void* const* d_in, const int* in_sizes, int n_in,
                              void* d_out, int out_size, void* d_ws, size_t ws_size,
                              hipStream_t stream) {
    const float* query   = (const float*)d_in[0];
    const float* key     = (const float*)d_in[1];
    const float* value   = (const float*)d_in[2];
    const float* Siprev  = (const float*)d_in[3];
    const float* Zi      = (const float*)d_in[4];
    const float* Pi      = (const float*)d_in[5];
    const float* Mi      = (const float*)d_in[6];
    const float* Uiprev  = (const float*)d_in[7];
    const float* Siprev2 = (const float*)d_in[8];
    float* out = (float*)d_out;

    const int nh = in_sizes[0] / 64;  // N*H = 8192
    fra_adamax_fused<<<nh, 256, 0, stream>>>(query, key, value, Siprev, Zi,
                                             Pi, Mi, Uiprev, Siprev2, out);
}